// Round 9
// baseline (339.353 us; speedup 1.0000x reference)
//
#include <hip/hip_runtime.h>
#include <stdint.h>

#define N_H    128
#define N_INV  96
#define N_IN   320
#define HS     132      // bf16 H-tile stride (128+4), measured 0 conflicts
#define EPSF   134      // f32 epilogue stride (2-way bank alias = free)
#define TILES  2
#define NWAVE  8
#define EPW    (TILES * 16)     // 32 edges per wave
#define EPB    (EPW * NWAVE)    // 256 edges per block
#define KS1    10
#define KS2    4
#define W1_BYTES 81920          // 10*8*64*16
#define W2_BYTES 32768          // 4*8*64*16
#define W_BYTES  (W1_BYTES + W2_BYTES)       // 114688
#define WBUF     4352           // per-wave buffer
#define SMEM_BYTES (W_BYTES + NWAVE * WBUF)  // 149504

typedef __bf16 bf16x8 __attribute__((ext_vector_type(8)));
typedef float  f32x4  __attribute__((ext_vector_type(4)));

__device__ __forceinline__ unsigned short f2bf(float f) {
    union { float f; unsigned u; } v; v.f = f;
    unsigned u = v.u;
    u += 0x7FFFu + ((u >> 16) & 1u);   // RNE
    return (unsigned short)(u >> 16);
}

// Pack weights in MFMA-fragment order, W1 then W2 contiguous (one linear
// 112KB region for block staging):
//   wpk[(ks*8+nt)*512 + lane*8 + j] = W[k=ks*32+(lane>>4)*8+j][n=nt*16+(lane&15)]
__global__ void prep_weights(const float* __restrict__ W1,
                             const float* __restrict__ W2,
                             unsigned short* __restrict__ w1p,
                             unsigned short* __restrict__ w2p) {
    int idx = blockIdx.x * blockDim.x + threadIdx.x;
    if (idx < KS1 * 8 * 64 * 8) {
        int j = idx & 7, lane = (idx >> 3) & 63, nt = (idx >> 9) & 7, ks = idx >> 12;
        int k = ks * 32 + (lane >> 4) * 8 + j;
        int n = nt * 16 + (lane & 15);
        w1p[idx] = f2bf(W1[(size_t)k * N_H + n]);
    } else {
        int r = idx - KS1 * 8 * 64 * 8;
        if (r < KS2 * 8 * 64 * 8) {
            int j = r & 7, lane = (r >> 3) & 63, nt = (r >> 9) & 7, ks = r >> 12;
            int k = ks * 32 + (lane >> 4) * 8 + j;
            int n = nt * 16 + (lane & 15);
            w2p[r] = f2bf(W2[(size_t)k * N_H + n]);
        }
    }
}

// node_invariant -> bf16 so each gather fragment is a single 16B load.
__global__ void prep_ninv(const float* __restrict__ ninv,
                          unsigned short* __restrict__ nb, int n4) {
    int i = blockIdx.x * blockDim.x + threadIdx.x;
    if (i < n4) {
        float4 v = ((const float4*)ninv)[i];
        ((ushort4*)nb)[i] = make_ushort4(f2bf(v.x), f2bf(v.y), f2bf(v.z), f2bf(v.w));
    }
}

// 8 waves/block, weights staged to LDS once per block. R9 change: ALL
// pre-GEMM1 VMEM (staging DMA, node gathers, ef fragments) is issued
// before the single __syncthreads, whose vmcnt(0) drain completes them
// together -> one exposed latency per block; GEMM1 runs with zero vmcnt
// waits. Register budget (2 waves/SIMD = 256) funds the 64-reg ef stash.
__global__ __launch_bounds__(512, 2)
void edge_mlp(const unsigned short* __restrict__ ninvb, const float* __restrict__ ef,
              const int* __restrict__ ei,
              const unsigned short* __restrict__ wpk,
              const float* __restrict__ b1, const float* __restrict__ b2,
              const float* __restrict__ gamma, const float* __restrict__ beta,
              float* __restrict__ out, int E) {
    extern __shared__ __align__(16) char smem[];

    const int tid  = threadIdx.x;
    const int wv   = tid >> 6;
    const int lane = tid & 63;
    const int lr   = lane & 15;
    const int lkg  = lane >> 4;
    const int lk   = lkg * 8;
    const int qr   = lkg * 4;

    const int ebase = (int)blockIdx.x * EPB + wv * EPW;

    // ---- (1) ei loads (oldest in queue) ----
    int e[TILES], s[TILES], d[TILES];
    #pragma unroll
    for (int t = 0; t < TILES; ++t) {
        int er = ebase + t * 16 + lr;
        e[t] = er < E ? er : E - 1;
    }
    #pragma unroll
    for (int t = 0; t < TILES; ++t) { s[t] = ei[e[t]]; d[t] = ei[(size_t)E + e[t]]; }

    // ---- (2) stage 112KB packed weights to LDS (14 x 1KB chunks per wave) ----
    {
        const char* gsrc = (const char*)wpk;
        #pragma unroll
        for (int i = 0; i < 14; ++i) {
            int c = wv * 14 + i;
            __builtin_amdgcn_global_load_lds(
                (const __attribute__((address_space(1))) void*)(gsrc + c * 1024 + lane * 16),
                (__attribute__((address_space(3))) void*)(smem + c * 1024),
                16, 0, 0);
        }
    }

    // ---- (3) node gathers: issued now, complete at the barrier ----
    bf16x8 an[TILES][6];
    #pragma unroll
    for (int t = 0; t < TILES; ++t) {
        #pragma unroll
        for (int q = 0; q < 6; ++q) {
            int row = q < 3 ? s[t] : d[t];
            an[t][q] = *(const bf16x8*)(ninvb + (size_t)row * N_INV + (q % 3) * 32 + lk);
        }
    }

    // ---- (4) ALL ef A-fragments issued now (64 f32 regs held over barrier) ----
    f32x4 efa[TILES][4][2];
    #pragma unroll
    for (int t = 0; t < TILES; ++t) {
        #pragma unroll
        for (int j = 0; j < 4; ++j) {
            const float* ap = ef + (size_t)e[t] * N_H + j * 32 + lk;
            efa[t][j][0] = *(const f32x4*)ap;
            efa[t][j][1] = *(const f32x4*)(ap + 4);
        }
    }

    __syncthreads();   // single drain: staging + gathers + ef all complete here

    // ---- GEMM1: zero vmcnt waits; pure LDS + VALU + MFMA ----
    f32x4 acc[TILES][8] = {};
    #pragma unroll
    for (int ks = 0; ks < KS1; ++ks) {
        bf16x8 bfr[8];
        #pragma unroll
        for (int nt = 0; nt < 8; ++nt)
            bfr[nt] = *(const bf16x8*)(smem + ((ks * 8 + nt) << 10) + (lane << 4));
        #pragma unroll
        for (int t = 0; t < TILES; ++t) {
            bf16x8 a;
            if (ks < 6) {
                a = an[t][ks];
            } else {
                const int j = ks - 6;
                union { unsigned short us[8]; bf16x8 b; } ua;
                ua.us[0] = f2bf(efa[t][j][0][0]); ua.us[1] = f2bf(efa[t][j][0][1]);
                ua.us[2] = f2bf(efa[t][j][0][2]); ua.us[3] = f2bf(efa[t][j][0][3]);
                ua.us[4] = f2bf(efa[t][j][1][0]); ua.us[5] = f2bf(efa[t][j][1][1]);
                ua.us[6] = f2bf(efa[t][j][1][2]); ua.us[7] = f2bf(efa[t][j][1][3]);
                a = ua.b;
            }
            #pragma unroll
            for (int nt = 0; nt < 8; ++nt)
                acc[t][nt] = __builtin_amdgcn_mfma_f32_16x16x32_bf16(a, bfr[nt], acc[t][nt], 0, 0, 0);
        }
    }

    char* buf = smem + W_BYTES + wv * WBUF;           // per-wave scratch
    unsigned short* hb = (unsigned short*)buf;
    float* ep = (float*)buf;

    #pragma unroll
    for (int t = 0; t < TILES; ++t) {
        // ---- bias + ReLU -> bf16 H tile (C/D layout: col=lane&15, row=qr+i) ----
        #pragma unroll
        for (int nt = 0; nt < 8; ++nt) {
            float bb = b1[nt * 16 + lr];
            #pragma unroll
            for (int i = 0; i < 4; ++i) {
                float v = acc[t][nt][i] + bb;
                v = v > 0.0f ? v : 0.0f;
                hb[(qr + i) * HS + nt * 16 + lr] = f2bf(v);
            }
        }
        __builtin_amdgcn_wave_barrier();

        // ---- residual loads issued here; GEMM2 (all-LDS) hides their latency ----
        f32x4 res[2][4];
        #pragma unroll
        for (int h = 0; h < 2; ++h) {
            #pragma unroll
            for (int it = 0; it < 4; ++it) {
                int cid = it * 64 + lane;
                int row = cid >> 5, c4 = (cid & 31) << 2;
                int erow = ebase + t * 16 + 8 * h + row;
                int ec = erow < E ? erow : E - 1;
                res[h][it] = *(const f32x4*)(ef + (size_t)ec * N_H + c4);
            }
        }

        // ---- GEMM2: both operands from LDS ----
        f32x4 acc2[8] = {};
        #pragma unroll
        for (int ks = 0; ks < KS2; ++ks) {
            bf16x8 a = *(const bf16x8*)((const char*)hb + lr * (HS * 2) + ks * 64 + lkg * 16);
            #pragma unroll
            for (int nt = 0; nt < 8; ++nt) {
                bf16x8 w = *(const bf16x8*)(smem + W1_BYTES + ((ks * 8 + nt) << 10) + (lane << 4));
                acc2[nt] = __builtin_amdgcn_mfma_f32_16x16x32_bf16(a, w, acc2[nt], 0, 0, 0);
            }
        }

        // ---- bias + LayerNorm ----
        float vals[8][4];
        float s1[4] = {0.f, 0.f, 0.f, 0.f};
        float s2[4] = {0.f, 0.f, 0.f, 0.f};
        #pragma unroll
        for (int nt = 0; nt < 8; ++nt) {
            float bb = b2[nt * 16 + lr];
            #pragma unroll
            for (int i = 0; i < 4; ++i) {
                float v = acc2[nt][i] + bb;
                vals[nt][i] = v;
                s1[i] += v;
                s2[i] += v * v;
            }
        }
        #pragma unroll
        for (int m = 1; m < 16; m <<= 1) {
            #pragma unroll
            for (int i = 0; i < 4; ++i) {
                s1[i] += __shfl_xor(s1[i], m);
                s2[i] += __shfl_xor(s2[i], m);
            }
        }
        float mu[4], rs[4];
        #pragma unroll
        for (int i = 0; i < 4; ++i) {
            mu[i] = s1[i] * (1.0f / 128.0f);
            float var = s2[i] * (1.0f / 128.0f) - mu[i] * mu[i];
            rs[i] = rsqrtf(var + 1e-5f);
        }

        // ---- epilogue in two 8-row halves through the f32 LDS buffer ----
        #pragma unroll
        for (int h = 0; h < 2; ++h) {
            if ((lkg >> 1) == h) {        // this lane's rows are in half h
                #pragma unroll
                for (int nt = 0; nt < 8; ++nt) {
                    int c = nt * 16 + lr;
                    float g  = gamma[c];
                    float bt = beta[c];
                    #pragma unroll
                    for (int i = 0; i < 4; ++i)
                        ep[(qr - 8 * h + i) * EPSF + c] = (vals[nt][i] - mu[i]) * rs[i] * g + bt;
                }
            }
            __builtin_amdgcn_wave_barrier();
            #pragma unroll
            for (int it = 0; it < 4; ++it) {
                int cid = it * 64 + lane;
                int row = cid >> 5, c4 = (cid & 31) << 2;
                int erow = ebase + t * 16 + 8 * h + row;
                if (erow < E) {
                    f32x4 nv = *(const f32x4*)(ep + row * EPSF + c4);
                    *(f32x4*)(out + (size_t)erow * N_H + c4) = nv + res[h][it];
                }
            }
            __builtin_amdgcn_wave_barrier();
        }
    }
}

extern "C" void kernel_launch(void* const* d_in, const int* in_sizes, int n_in,
                              void* d_out, int out_size, void* d_ws, size_t ws_size,
                              hipStream_t stream) {
    const float* ninv = (const float*)d_in[0];
    const float* ef   = (const float*)d_in[1];
    const int*   ei   = (const int*)d_in[2];
    const float* W1   = (const float*)d_in[3];
    const float* b1   = (const float*)d_in[4];
    const float* W2   = (const float*)d_in[5];
    const float* b2   = (const float*)d_in[6];
    const float* g    = (const float*)d_in[7];
    const float* bt   = (const float*)d_in[8];
    float* out = (float*)d_out;

    const int E = in_sizes[1] / N_H;
    const int NNODE = in_sizes[0] / N_INV;

    unsigned short* w1p = (unsigned short*)d_ws;             // 40960 bf16
    unsigned short* w2p = w1p + KS1 * 8 * 64 * 8;            // 16384 bf16 (contiguous)
    unsigned short* nb  = w2p + KS2 * 8 * 64 * 8;            // NNODE*96 bf16

    hipFuncSetAttribute((const void*)edge_mlp,
                        hipFuncAttributeMaxDynamicSharedMemorySize, SMEM_BYTES);

    int prep_total = (KS1 + KS2) * 8 * 64 * 8;
    prep_weights<<<(prep_total + 255) / 256, 256, 0, stream>>>(W1, W2, w1p, w2p);

    int n4 = NNODE * N_INV / 4;
    prep_ninv<<<(n4 + 255) / 256, 256, 0, stream>>>(ninv, nb, n4);

    int nblk = (E + EPB - 1) / EPB;
    edge_mlp<<<nblk, 512, SMEM_BYTES, stream>>>(nb, ef, ei, w1p, b1, b2, g, bt, out, E);
}

// Round 10
// 261.634 us; speedup vs baseline: 1.2971x; 1.2971x over previous
//
#include <hip/hip_runtime.h>
#include <stdint.h>

#define N_H    128
#define N_INV  96
#define HS     132      // bf16 H-tile stride (128+4)
#define EPSF   134      // f32 epilogue stride
#define TILES  2
#define NWAVE  8
#define CHUNK  256      // edges per chunk = 8 waves x 32
#define NBLK   256      // persistent blocks; LDS pins exactly 1 per CU
#define KS1    10
#define KS2    4
#define W1_BYTES 81920
#define W2_BYTES 32768
#define W_BYTES  (W1_BYTES + W2_BYTES)        // 114688
#define WBUF     4352
#define BIAS_OFF (W_BYTES + NWAVE * WBUF)     // 149504
#define SMEM_BYTES (BIAS_OFF + 2048)          // 151552

typedef __bf16 bf16x8 __attribute__((ext_vector_type(8)));
typedef float  f32x4  __attribute__((ext_vector_type(4)));

__device__ __forceinline__ unsigned short f2bf(float f) {
    union { float f; unsigned u; } v; v.f = f;
    unsigned u = v.u;
    u += 0x7FFFu + ((u >> 16) & 1u);   // RNE
    return (unsigned short)(u >> 16);
}

// Pack weights in MFMA-fragment order, W1 then W2 contiguous:
//   wpk[(ks*8+nt)*512 + lane*8 + j] = W[k=ks*32+(lane>>4)*8+j][n=nt*16+(lane&15)]
__global__ void prep_weights(const float* __restrict__ W1,
                             const float* __restrict__ W2,
                             unsigned short* __restrict__ w1p,
                             unsigned short* __restrict__ w2p) {
    int idx = blockIdx.x * blockDim.x + threadIdx.x;
    if (idx < KS1 * 8 * 64 * 8) {
        int j = idx & 7, lane = (idx >> 3) & 63, nt = (idx >> 9) & 7, ks = idx >> 12;
        int k = ks * 32 + (lane >> 4) * 8 + j;
        int n = nt * 16 + (lane & 15);
        w1p[idx] = f2bf(W1[(size_t)k * N_H + n]);
    } else {
        int r = idx - KS1 * 8 * 64 * 8;
        if (r < KS2 * 8 * 64 * 8) {
            int j = r & 7, lane = (r >> 3) & 63, nt = (r >> 9) & 7, ks = r >> 12;
            int k = ks * 32 + (lane >> 4) * 8 + j;
            int n = nt * 16 + (lane & 15);
            w2p[r] = f2bf(W2[(size_t)k * N_H + n]);
        }
    }
}

// node_invariant -> bf16 so each gather fragment is a single 16B load.
__global__ void prep_ninv(const float* __restrict__ ninv,
                          unsigned short* __restrict__ nb, int n4) {
    int i = blockIdx.x * blockDim.x + threadIdx.x;
    if (i < n4) {
        float4 v = ((const float4*)ninv)[i];
        ((ushort4*)nb)[i] = make_ushort4(f2bf(v.x), f2bf(v.y), f2bf(v.z), f2bf(v.w));
    }
}

// Persistent: 256 blocks (1/CU), weights staged once, then a barrier-free
// per-wave loop over ~12 chunks of 256 edges with loop-carried prefetch:
// ei two chunks ahead, gathers/ef one chunk ahead, residual under GEMM2.
__global__ __launch_bounds__(512, 2)
void edge_mlp(const unsigned short* __restrict__ ninvb, const float* __restrict__ ef,
              const int* __restrict__ ei,
              const unsigned short* __restrict__ wpk,
              const float* __restrict__ b1g, const float* __restrict__ b2g,
              const float* __restrict__ gg, const float* __restrict__ btg,
              float* __restrict__ out, int E, int cbase, int crem) {
    extern __shared__ __align__(16) char smem[];

    const int tid  = threadIdx.x;
    const int wv   = tid >> 6;
    const int lane = tid & 63;
    const int lr   = lane & 15;
    const int lkg  = lane >> 4;
    const int lk   = lkg * 8;
    const int qr   = lkg * 4;

    const int b     = blockIdx.x;
    const int c0    = b * cbase + (b < crem ? b : crem);
    const int cnt   = cbase + (b < crem ? 1 : 0);
    if (cnt <= 0) return;
    const int clast = c0 + cnt - 1;

    // ---- stage 112KB weights + 2KB bias/ln params into LDS ----
    {
        const char* gsrc = (const char*)wpk;
        #pragma unroll
        for (int i = 0; i < 14; ++i) {
            int ch = wv * 14 + i;
            __builtin_amdgcn_global_load_lds(
                (const __attribute__((address_space(1))) void*)(gsrc + ch * 1024 + lane * 16),
                (__attribute__((address_space(3))) void*)(smem + ch * 1024),
                16, 0, 0);
        }
        if (wv == 0) {
            const float* srcs[4] = { b1g, b2g, gg, btg };
            #pragma unroll
            for (int a = 0; a < 4; ++a) {
                #pragma unroll
                for (int h = 0; h < 2; ++h) {
                    __builtin_amdgcn_global_load_lds(
                        (const __attribute__((address_space(1))) void*)(srcs[a] + h * 64 + lane),
                        (__attribute__((address_space(3))) void*)(smem + BIAS_OFF + a * 512 + h * 256),
                        4, 0, 0);
                }
            }
        }
    }

    const float* b1l = (const float*)(smem + BIAS_OFF);
    const float* b2l = (const float*)(smem + BIAS_OFF + 512);
    const float* gl  = (const float*)(smem + BIAS_OFF + 1024);
    const float* btl = (const float*)(smem + BIAS_OFF + 1536);

    // ---- per-wave prologue: chunk c0 gathers/ef; ei for c0+1, c0+2 ----
    bf16x8 an[TILES][6];
    f32x4  efa[TILES][4][2];
    int sA[TILES], dA[TILES], eS[TILES], eD[TILES];
    {
        #pragma unroll
        for (int t = 0; t < TILES; ++t) {
            int er = c0 * CHUNK + wv * 32 + t * 16 + lr;
            int ee = er < E ? er : E - 1;
            int s0 = ei[ee], d0 = ei[(size_t)E + ee];
            #pragma unroll
            for (int q = 0; q < 6; ++q) {
                int row = q < 3 ? s0 : d0;
                an[t][q] = *(const bf16x8*)(ninvb + (size_t)row * N_INV + (q % 3) * 32 + lk);
            }
            const float* ap = ef + (size_t)ee * N_H;
            #pragma unroll
            for (int j = 0; j < 4; ++j) {
                efa[t][j][0] = *(const f32x4*)(ap + j * 32 + lk);
                efa[t][j][1] = *(const f32x4*)(ap + j * 32 + lk + 4);
            }
        }
        int c1 = c0 + 1 <= clast ? c0 + 1 : clast;
        #pragma unroll
        for (int t = 0; t < TILES; ++t) {
            int er = c1 * CHUNK + wv * 32 + t * 16 + lr;
            int ee = er < E ? er : E - 1;
            sA[t] = ei[ee]; dA[t] = ei[(size_t)E + ee];
        }
        int c2 = c0 + 2 <= clast ? c0 + 2 : clast;
        #pragma unroll
        for (int t = 0; t < TILES; ++t) {
            int er = c2 * CHUNK + wv * 32 + t * 16 + lr;
            int ee = er < E ? er : E - 1;
            eS[t] = ei[ee]; eD[t] = ei[(size_t)E + ee];
        }
    }

    __syncthreads();   // the only block-wide barrier

    char* buf = smem + W_BYTES + wv * WBUF;
    unsigned short* hb = (unsigned short*)buf;
    float* ep = (float*)buf;

    for (int c = c0; c <= clast; ++c) {
        // ---- GEMM1(c): A from regs (gathers + converted ef), B from LDS ----
        f32x4 acc[TILES][8] = {};
        #pragma unroll
        for (int ks = 0; ks < KS1; ++ks) {
            bf16x8 bfr[8];
            #pragma unroll
            for (int nt = 0; nt < 8; ++nt)
                bfr[nt] = *(const bf16x8*)(smem + ((ks * 8 + nt) << 10) + (lane << 4));
            #pragma unroll
            for (int t = 0; t < TILES; ++t) {
                bf16x8 a;
                if (ks < 6) {
                    a = an[t][ks];
                } else {
                    const int j = ks - 6;
                    union { unsigned short us[8]; bf16x8 b; } ua;
                    ua.us[0] = f2bf(efa[t][j][0][0]); ua.us[1] = f2bf(efa[t][j][0][1]);
                    ua.us[2] = f2bf(efa[t][j][0][2]); ua.us[3] = f2bf(efa[t][j][0][3]);
                    ua.us[4] = f2bf(efa[t][j][1][0]); ua.us[5] = f2bf(efa[t][j][1][1]);
                    ua.us[6] = f2bf(efa[t][j][1][2]); ua.us[7] = f2bf(efa[t][j][1][3]);
                    a = ua.b;
                }
                #pragma unroll
                for (int nt = 0; nt < 8; ++nt)
                    acc[t][nt] = __builtin_amdgcn_mfma_f32_16x16x32_bf16(a, bfr[nt], acc[t][nt], 0, 0, 0);
            }
        }

        const int eb = c * CHUNK + wv * 32;

        #pragma unroll
        for (int t = 0; t < TILES; ++t) {
            // ---- bias + ReLU -> bf16 H tile ----
            #pragma unroll
            for (int nt = 0; nt < 8; ++nt) {
                float bb = b1l[nt * 16 + lr];
                #pragma unroll
                for (int i = 0; i < 4; ++i) {
                    float v = acc[t][nt][i] + bb;
                    v = v > 0.0f ? v : 0.0f;
                    hb[(qr + i) * HS + nt * 16 + lr] = f2bf(v);
                }
            }
            __builtin_amdgcn_wave_barrier();

            // ---- residual loads; GEMM2 hides their latency ----
            f32x4 res[2][4];
            #pragma unroll
            for (int h = 0; h < 2; ++h) {
                #pragma unroll
                for (int it = 0; it < 4; ++it) {
                    int cid = it * 64 + lane;
                    int row = cid >> 5, c4 = (cid & 31) << 2;
                    int erow = eb + t * 16 + 8 * h + row;
                    int ec = erow < E ? erow : E - 1;
                    res[h][it] = *(const f32x4*)(ef + (size_t)ec * N_H + c4);
                }
            }

            // ---- GEMM2: all-LDS ----
            f32x4 acc2[8] = {};
            #pragma unroll
            for (int ks = 0; ks < KS2; ++ks) {
                bf16x8 a = *(const bf16x8*)((const char*)hb + lr * (HS * 2) + ks * 64 + lkg * 16);
                #pragma unroll
                for (int nt = 0; nt < 8; ++nt) {
                    bf16x8 w = *(const bf16x8*)(smem + W1_BYTES + ((ks * 8 + nt) << 10) + (lane << 4));
                    acc2[nt] = __builtin_amdgcn_mfma_f32_16x16x32_bf16(a, w, acc2[nt], 0, 0, 0);
                }
            }

            if (t == 0) {
                // ---- issue gathers(c+1) using sA/dA (ei one ahead) ----
                #pragma unroll
                for (int tt = 0; tt < TILES; ++tt) {
                    #pragma unroll
                    for (int q = 0; q < 6; ++q) {
                        int row = q < 3 ? sA[tt] : dA[tt];
                        an[tt][q] = *(const bf16x8*)(ninvb + (size_t)row * N_INV + (q % 3) * 32 + lk);
                    }
                }
                // rotate ei pipeline: sA <- eS (chunk c+2); issue eS <- ei(c+3)
                sA[0] = eS[0]; sA[1] = eS[1]; dA[0] = eD[0]; dA[1] = eD[1];
                int c3 = c + 3 <= clast ? c + 3 : clast;
                #pragma unroll
                for (int tt = 0; tt < TILES; ++tt) {
                    int er = c3 * CHUNK + wv * 32 + tt * 16 + lr;
                    int ee = er < E ? er : E - 1;
                    eS[tt] = ei[ee]; eD[tt] = ei[(size_t)E + ee];
                }
            }

            // ---- bias + LayerNorm ----
            float vals[8][4];
            float s1[4] = {0.f, 0.f, 0.f, 0.f};
            float s2[4] = {0.f, 0.f, 0.f, 0.f};
            #pragma unroll
            for (int nt = 0; nt < 8; ++nt) {
                float bb = b2l[nt * 16 + lr];
                #pragma unroll
                for (int i = 0; i < 4; ++i) {
                    float v = acc2[nt][i] + bb;
                    vals[nt][i] = v;
                    s1[i] += v;
                    s2[i] += v * v;
                }
            }
            #pragma unroll
            for (int m = 1; m < 16; m <<= 1) {
                #pragma unroll
                for (int i = 0; i < 4; ++i) {
                    s1[i] += __shfl_xor(s1[i], m);
                    s2[i] += __shfl_xor(s2[i], m);
                }
            }
            float mu[4], rs[4];
            #pragma unroll
            for (int i = 0; i < 4; ++i) {
                mu[i] = s1[i] * (1.0f / 128.0f);
                float var = s2[i] * (1.0f / 128.0f) - mu[i] * mu[i];
                rs[i] = rsqrtf(var + 1e-5f);
            }

            // ---- epilogue: two 8-row halves through the f32 LDS buffer ----
            #pragma unroll
            for (int h = 0; h < 2; ++h) {
                if ((lkg >> 1) == h) {
                    #pragma unroll
                    for (int nt = 0; nt < 8; ++nt) {
                        int cc = nt * 16 + lr;
                        float g  = gl[cc];
                        float bt = btl[cc];
                        #pragma unroll
                        for (int i = 0; i < 4; ++i)
                            ep[(qr - 8 * h + i) * EPSF + cc] = (vals[nt][i] - mu[i]) * rs[i] * g + bt;
                    }
                }
                __builtin_amdgcn_wave_barrier();
                #pragma unroll
                for (int it = 0; it < 4; ++it) {
                    int cid = it * 64 + lane;
                    int row = cid >> 5, c4 = (cid & 31) << 2;
                    int erow = eb + t * 16 + 8 * h + row;
                    if (erow < E) {
                        f32x4 nv = *(const f32x4*)(ep + row * EPSF + c4);
                        *(f32x4*)(out + (size_t)erow * N_H + c4) = nv + res[h][it];
                    }
                }
                __builtin_amdgcn_wave_barrier();
            }
        }

        // ---- issue ef fragments (c+1); GEMM1(c+1) ks0-5 covers the latency ----
        {
            int cn = c + 1 <= clast ? c + 1 : clast;
            #pragma unroll
            for (int t = 0; t < TILES; ++t) {
                int er = cn * CHUNK + wv * 32 + t * 16 + lr;
                int ee = er < E ? er : E - 1;
                const float* ap = ef + (size_t)ee * N_H;
                #pragma unroll
                for (int j = 0; j < 4; ++j) {
                    efa[t][j][0] = *(const f32x4*)(ap + j * 32 + lk);
                    efa[t][j][1] = *(const f32x4*)(ap + j * 32 + lk + 4);
                }
            }
        }
    }
}

extern "C" void kernel_launch(void* const* d_in, const int* in_sizes, int n_in,
                              void* d_out, int out_size, void* d_ws, size_t ws_size,
                              hipStream_t stream) {
    const float* ninv = (const float*)d_in[0];
    const float* ef   = (const float*)d_in[1];
    const int*   ei   = (const int*)d_in[2];
    const float* W1   = (const float*)d_in[3];
    const float* b1   = (const float*)d_in[4];
    const float* W2   = (const float*)d_in[5];
    const float* b2   = (const float*)d_in[6];
    const float* g    = (const float*)d_in[7];
    const float* bt   = (const float*)d_in[8];
    float* out = (float*)d_out;

    const int E = in_sizes[1] / N_H;
    const int NNODE = in_sizes[0] / N_INV;

    unsigned short* w1p = (unsigned short*)d_ws;             // 40960 bf16
    unsigned short* w2p = w1p + KS1 * 8 * 64 * 8;            // 16384 bf16 (contiguous)
    unsigned short* nb  = w2p + KS2 * 8 * 64 * 8;            // NNODE*96 bf16

    hipFuncSetAttribute((const void*)edge_mlp,
                        hipFuncAttributeMaxDynamicSharedMemorySize, SMEM_BYTES);

    int prep_total = (KS1 + KS2) * 8 * 64 * 8;
    prep_weights<<<(prep_total + 255) / 256, 256, 0, stream>>>(W1, W2, w1p, w2p);

    int n4 = NNODE * N_INV / 4;
    prep_ninv<<<(n4 + 255) / 256, 256, 0, stream>>>(ninv, nb, n4);

    int nchunks = (E + CHUNK - 1) / CHUNK;
    int cbase = nchunks / NBLK;
    int crem  = nchunks - cbase * NBLK;
    edge_mlp<<<NBLK, 512, SMEM_BYTES, stream>>>(nb, ef, ei, w1p, b1, b2, g, bt,
                                                out, E, cbase, crem);
}